// Round 9
// baseline (190.383 us; speedup 1.0000x reference)
//
#include <hip/hip_runtime.h>

#define BB 4
#define CC 3
#define HH 512
#define WW 512
#define NS 81              // 9 x 9 shifts
#define IMG (HH * WW)
#define CHW (CC * IMG)
#define STRIP 32           // rows per k_sims block (8 rows per wave)
#define NSTRIP (HH / STRIP)              // 16
#define NBC (BB * CC)                    // 12
#define NBLK9 (NBC * NSTRIP)             // 192 blocks per sx  (192 % 8 == 0)
#define NBLK (NBLK9 * 9)                 // 1728

// ws layout: float partials[NBLK][9] at byte 0 (~62 KB); int best[BB*2] after.
#define BEST_OFF (NBLK * 9 * sizeof(float))

// sim(b,sx,sy) = sum over c,i,j (both (i,j) and (i+sx,j+sy) in bounds) of
//               x[b,c,i,j] * x_ref[b,c,i+sx,j+sy]
// R8 skeleton + 3 fixes:
//  (a) branch-free body: ref row clamped, x scaled by 0/1 row mask -> all
//      loads unconditional straight-line (R8's `continue` blocked hoisting).
//  (b) explicit 2-deep double buffer via macros (no address-taken locals).
//  (c) XCD swizzle: bid = sxi*192 + (bc*16+strip); 192%8==0 so all 9 sx of a
//      strip hit the SAME XCD's L2; consecutive blocks = disjoint strips.
__global__ __launch_bounds__(256, 4) void k_sims(const float* __restrict__ xref,
                                                 const float* __restrict__ x,
                                                 float* __restrict__ partials) {
    int bid  = blockIdx.x;
    int sxi  = bid / NBLK9;              // sx = sxi - 4
    int rem  = bid % NBLK9;
    int bc   = rem / NSTRIP;
    int strip = rem % NSTRIP;
    const float* xp = x    + (size_t)bc * IMG;
    const float* rp = xref + (size_t)bc * IMG;
    int tid  = threadIdx.x;
    int lane = tid & 63;
    int wave = tid >> 6;
    int j0   = lane << 3;                // 8 floats per lane
    int sx   = sxi - 4;
    int ip0  = strip * STRIP + wave * 8;

    float acc[9];
#pragma unroll
    for (int s = 0; s < 9; ++s) acc[s] = 0.f;

    float4 xa[2], xb[2], ra[2], rb[2];
    float  wm[2];

#define LOADIT(RR, BUF)                                                      \
    {                                                                        \
        int ip  = ip0 + (RR);                                                \
        int ii  = ip + sx;                                                   \
        int iic = ii < 0 ? 0 : (ii > HH - 1 ? HH - 1 : ii);                  \
        wm[BUF] = ((unsigned)ii < HH) ? 1.f : 0.f;                           \
        const float* xrow = xp + ip * WW + j0;                               \
        const float* rrow = rp + iic * WW + j0;                              \
        xa[BUF] = *(const float4*)(xrow);                                    \
        xb[BUF] = *(const float4*)(xrow + 4);                                \
        ra[BUF] = *(const float4*)(rrow);                                    \
        rb[BUF] = *(const float4*)(rrow + 4);                                \
    }

#define C4(v, i) ((i) == 0 ? (v).x : (i) == 1 ? (v).y : (i) == 2 ? (v).z : (v).w)

    LOADIT(0, 0)
#pragma unroll
    for (int rr = 0; rr < 8; ++rr) {
        if (rr < 7) LOADIT(rr + 1, (rr + 1) & 1)      // prefetch next iter
        int B = rr & 1;
        // halo: p = ref cols j0-4..j0-1 (lane-1's rb), n = j0+8..j0+11
        float p0 = __shfl_up(rb[B].x, 1, 64);
        float p1 = __shfl_up(rb[B].y, 1, 64);
        float p2 = __shfl_up(rb[B].z, 1, 64);
        float p3 = __shfl_up(rb[B].w, 1, 64);
        if (lane == 0) { p0 = p1 = p2 = p3 = 0.f; }   // cols < 0 -> mask
        float n0 = __shfl_down(ra[B].x, 1, 64);
        float n1 = __shfl_down(ra[B].y, 1, 64);
        float n2 = __shfl_down(ra[B].z, 1, 64);
        float n3 = __shfl_down(ra[B].w, 1, 64);
        if (lane == 63) { n0 = n1 = n2 = n3 = 0.f; }  // cols >= 512 -> mask

        float m = wm[B];                 // 0/1 row mask folded into x
        float q0 = xa[B].x * m, q1 = xa[B].y * m, q2 = xa[B].z * m, q3 = xa[B].w * m;
        float q4 = xb[B].x * m, q5 = xb[B].y * m, q6 = xb[B].z * m, q7 = xb[B].w * m;

#define P4(i) ((i) == 0 ? p0 : (i) == 1 ? p1 : (i) == 2 ? p2 : p3)
#define N4(i) ((i) == 0 ? n0 : (i) == 1 ? n1 : (i) == 2 ? n2 : n3)
#define XQ(k) ((k) == 0 ? q0 : (k) == 1 ? q1 : (k) == 2 ? q2 : (k) == 3 ? q3 : \
               (k) == 4 ? q4 : (k) == 5 ? q5 : (k) == 6 ? q6 : q7)
#pragma unroll
        for (int syi = 0; syi < 9; ++syi) {
#pragma unroll
            for (int k = 0; k < 8; ++k) {
                int i = k + syi;         // window index 0..15 (constant)
                float wv = (i < 4)  ? P4(i)
                         : (i < 8)  ? C4(ra[B], i - 4)
                         : (i < 12) ? C4(rb[B], i - 8)
                         :            N4(i - 12);
                acc[syi] += XQ(k) * wv;
            }
        }
#undef P4
#undef N4
#undef XQ
    }

    // wave reduce (fp32), block combine in LDS, direct store (no atomics)
    __shared__ float part[4][9];
#pragma unroll
    for (int s = 0; s < 9; ++s) {
        float v = acc[s];
        for (int off = 32; off; off >>= 1) v += __shfl_down(v, off, 64);
        if (lane == 0) part[wave][s] = v;
    }
    __syncthreads();
    if (tid < 9)
        partials[bid * 9 + tid] = part[0][tid] + part[1][tid]
                                + part[2][tid] + part[3][tid];
}

// One block (512 threads) per batch: parallel fp64 reduce of the 48 partials
// per shift-slot (6 threads/slot, 8 independent loads each), then argmax with
// first-index tie-break (strict > keeps lowest index).
__global__ __launch_bounds__(512) void k_argmax(const float* __restrict__ partials,
                                                int* __restrict__ best,
                                                float* __restrict__ outTail) {
    int b = blockIdx.x;
    int t = threadIdx.x;
    __shared__ double lds[486];
    __shared__ double vals[NS];
    if (t < 486) {
        int slot = t / 6;                 // 0..80
        int sub  = t % 6;
        int sxi = slot / 9, syi = slot % 9;
        double acc = 0.0;
#pragma unroll
        for (int k = 0; k < 8; ++k) {     // 8 values each
            int q  = sub * 8 + k;         // q in [0, 48)
            int c  = q >> 4;              // q / 16
            int st = q & 15;              // q % 16
            int pb = sxi * NBLK9 + (b * CC + c) * NSTRIP + st;   // swizzled layout
            acc += (double)partials[pb * 9 + syi];
        }
        lds[t] = acc;
    }
    __syncthreads();
    if (t < NS) {
        double s = 0.0;
#pragma unroll
        for (int k = 0; k < 6; ++k) s += lds[t * 6 + k];
        vals[t] = s;
    }
    __syncthreads();
    if (t == 0) {
        double bv = vals[0];
        int bi = 0;
        for (int s = 1; s < NS; ++s)
            if (vals[s] > bv) { bv = vals[s]; bi = s; }
        int sx = bi / 9 - 4;
        int sy = bi % 9 - 4;
        best[b * 2]     = sx;
        best[b * 2 + 1] = sy;
        outTail[b * 2]     = (float)sx;
        outTail[b * 2 + 1] = (float)sy;
    }
}

// out[b,c,i,j] = in-bounds(i-sx, j-sy) ? x[b,c,i-sx,j-sy] : 0
// One block = 2 rows of one (b,c) image; fast path = offset float4 load.
__global__ __launch_bounds__(256) void k_apply(const float* __restrict__ x,
                                               const int* __restrict__ best,
                                               float* __restrict__ out) {
    int blk = blockIdx.x;
    int bc  = blk >> 8;                 // 256 blocks per image (512 rows / 2)
    int tid = threadIdx.x;
    int row = ((blk & 255) << 1) + (tid >> 7);
    int j0  = (tid & 127) << 2;
    int b   = bc / CC;                  // block-uniform -> scalar loads of best
    int sx  = best[b * 2];
    int sy  = best[b * 2 + 1];
    int is  = row - sx;
    float4 v = make_float4(0.f, 0.f, 0.f, 0.f);
    if ((unsigned)is < HH) {
        const float* src = x + (size_t)bc * IMG + is * WW;
        int js0 = j0 - sy;
        if (js0 >= 0 && js0 + 3 < WW) {
            v = *(const float4*)(src + js0);   // 4B-aligned dwordx4, exact (R2-R8)
        } else {
            float* vv = (float*)&v;
#pragma unroll
            for (int k = 0; k < 4; ++k) {
                int js = js0 + k;
                if ((unsigned)js < WW) vv[k] = src[js];
            }
        }
    }
    *(float4*)(out + (size_t)bc * IMG + row * WW + j0) = v;
}

extern "C" void kernel_launch(void* const* d_in, const int* in_sizes, int n_in,
                              void* d_out, int out_size, void* d_ws, size_t ws_size,
                              hipStream_t stream) {
    const float* xref = (const float*)d_in[0];
    const float* x    = (const float*)d_in[1];
    float* out = (float*)d_out;

    float* partials = (float*)d_ws;
    int*   best     = (int*)((char*)d_ws + BEST_OFF);

    k_sims<<<NBLK, 256, 0, stream>>>(xref, x, partials);

    k_argmax<<<BB, 512, 0, stream>>>(partials, best, out + (size_t)BB * CHW);

    int applyBlocks = (BB * CC * HH) / 2;   // 3072
    k_apply<<<applyBlocks, 256, 0, stream>>>(x, best, out);
}

// Round 10
// 114.212 us; speedup vs baseline: 1.6669x; 1.6669x over previous
//
#include <hip/hip_runtime.h>

#define BB 4
#define CC 3
#define HH 512
#define WW 512
#define NS 81              // 9 x 9 shifts
#define IMG (HH * WW)
#define CHW (CC * IMG)
#define STRIP 16           // x rows per k_sims block (4 rows per wave)
#define NSTRIP (HH / STRIP)              // 32
#define NSXG 3                           // 3 sx per block
#define NBC (BB * CC)                    // 12
#define NBLK (NBC * NSTRIP * NSXG)       // 1152

// ws layout: float partials[NBLK][27] at byte 0 (~124 KB); int best[BB*2] at 128K.
#define BEST_OFF (128 * 1024)

// async global->LDS, 16B per lane, wave-uniform LDS base (m97 pattern)
#define GLD16(gptr, lptr)                                                     \
    __builtin_amdgcn_global_load_lds(                                         \
        (const __attribute__((address_space(1))) unsigned int*)(gptr),        \
        (__attribute__((address_space(3))) unsigned int*)(lptr), 16, 0, 0)

// constant-index component select (folds after full unroll)
#define C4(v, i) ((i) == 0 ? (v).x : (i) == 1 ? (v).y : (i) == 2 ? (v).z : (v).w)

// wave64 sum via DPP (VALU pipe, not DS): row_shr 1/2/4/8 + bcast15 + bcast31.
// Result lands in lane 63. bound_ctrl=true -> OOB reads 0.
#define DPP_ADD(r, ctrl, rmask)                                               \
    r += __int_as_float(__builtin_amdgcn_update_dpp(                          \
        0, __float_as_int(r), ctrl, rmask, 0xf, true));

// sim(b,sx,sy) = sum over c,i,j (both (i,j) and (i+sx,j+sy) in bounds) of
//               x[b,c,i,j] * x_ref[b,c,i+sx,j+sy]
// Block = (bc, 16-row strip, 3 consecutive sx). The fix for the 35-47us
// latency floor seen in R2-R9: ref rows staged ONCE per block into LDS via
// async global_load_lds (latency paid once, behind one barrier); the wave's
// 4 x-rows prefetched into NAMED float4s before that barrier. The compute
// loop touches only LDS + registers. Reduction via DPP (VALU), not shfl (DS).
// NO vector-typed local arrays anywhere (R6/R7/R9 scratch trauma).
__global__ __launch_bounds__(256, 4) void k_sims(const float* __restrict__ xref,
                                                 const float* __restrict__ x,
                                                 float* __restrict__ partials) {
    int bid  = blockIdx.x;
    int sxg  = bid % NSXG;
    int rem  = bid / NSXG;
    int strip = rem % NSTRIP;
    int bc   = rem / NSTRIP;
    int r0   = strip * STRIP;
    int s0   = sxg * 3 - 4;              // first sx of this block
    const float* xp = x    + (size_t)bc * IMG;
    const float* rp = xref + (size_t)bc * IMG;
    int tid  = threadIdx.x;
    int lane = tid & 63;
    int wave = tid >> 6;
    int j0   = lane << 3;                // 8 floats per lane

    // 18 ref rows [r0+s0, r0+s0+18), each padded +-4 cols (520 floats/row).
    __shared__ float rs[18][520];
    __shared__ float part[4][27];

    // issue async DMA: 36 chunks (18 rows x 2 halves), wave w takes c%4==w
    for (int c = wave; c < 36; c += 4) {
        int t  = c >> 1;                 // staged row 0..17
        int h  = c & 1;                  // half of the row
        int gr = r0 + s0 + t;
        gr = gr < 0 ? 0 : (gr > HH - 1 ? HH - 1 : gr);   // clamp (masked later)
        GLD16(rp + gr * WW + h * 256 + lane * 4, &rs[t][4 + h * 256]);
    }
    // zero the +-4 col pads (18 rows x 8 floats)
    if (tid < 144) {
        int t = tid >> 3, p = tid & 7;
        rs[t][p < 4 ? p : 512 + p] = 0.f;
    }

    // prefetch this wave's 4 x rows into named regs (overlaps the DMA drain)
    const float* xr0 = xp + (r0 + wave * 4 + 0) * WW + j0;
    const float* xr1 = xp + (r0 + wave * 4 + 1) * WW + j0;
    const float* xr2 = xp + (r0 + wave * 4 + 2) * WW + j0;
    const float* xr3 = xp + (r0 + wave * 4 + 3) * WW + j0;
    float4 xa0 = *(const float4*)(xr0), xb0 = *(const float4*)(xr0 + 4);
    float4 xa1 = *(const float4*)(xr1), xb1 = *(const float4*)(xr1 + 4);
    float4 xa2 = *(const float4*)(xr2), xb2 = *(const float4*)(xr2 + 4);
    float4 xa3 = *(const float4*)(xr3), xb3 = *(const float4*)(xr3 + 4);

    asm volatile("s_waitcnt vmcnt(0)" ::: "memory");   // DMA + x loads done
    __syncthreads();

    float acc[27];
#pragma unroll
    for (int s = 0; s < 27; ++s) acc[s] = 0.f;

#define XA(rr) ((rr) == 0 ? xa0 : (rr) == 1 ? xa1 : (rr) == 2 ? xa2 : xa3)
#define XB(rr) ((rr) == 0 ? xb0 : (rr) == 1 ? xb1 : (rr) == 2 ? xb2 : xb3)
#pragma unroll
    for (int rr = 0; rr < 4; ++rr) {
        int ip = r0 + wave * 4 + rr;     // x row (always in bounds)
#pragma unroll
        for (int sxl = 0; sxl < 3; ++sxl) {
            int ii = ip + s0 + sxl;      // ref row (wave-uniform test)
            if ((unsigned)ii >= HH) continue;
            int lr = wave * 4 + rr + sxl;          // staged row index
            const float* w0 = &rs[lr][j0];         // = ref cols j0-4 .. j0-1
            float4 c0 = *(const float4*)(w0);      // (pad col offset +4)
            float4 c1 = *(const float4*)(w0 + 4);  // ref cols j0   .. j0+3
            float4 c2 = *(const float4*)(w0 + 8);  // ref cols j0+4 .. j0+7
            float4 c3 = *(const float4*)(w0 + 12); // ref cols j0+8 .. j0+11
#pragma unroll
            for (int syi = 0; syi < 9; ++syi) {
#pragma unroll
                for (int k = 0; k < 8; ++k) {
                    int i = k + syi;     // window index 0..15 (constant)
                    float wv = (i < 4)  ? C4(c0, i)
                             : (i < 8)  ? C4(c1, i - 4)
                             : (i < 12) ? C4(c2, i - 8)
                             :            C4(c3, i - 12);
                    float xv = (k < 4) ? C4(XA(rr), k) : C4(XB(rr), k - 4);
                    acc[sxl * 9 + syi] += xv * wv;
                }
            }
        }
    }
#undef XA
#undef XB

    // wave reduce on the VALU pipe (DPP), block combine in LDS
#pragma unroll
    for (int s = 0; s < 27; ++s) {
        float r = acc[s];
        DPP_ADD(r, 0x111, 0xf)           // row_shr:1
        DPP_ADD(r, 0x112, 0xf)           // row_shr:2
        DPP_ADD(r, 0x114, 0xf)           // row_shr:4
        DPP_ADD(r, 0x118, 0xf)           // row_shr:8
        DPP_ADD(r, 0x142, 0xa)           // row_bcast:15 -> rows 1,3
        DPP_ADD(r, 0x143, 0xc)           // row_bcast:31 -> rows 2,3
        if (lane == 63) part[wave][s] = r;
    }
    __syncthreads();
    if (tid < 27)
        partials[bid * 27 + tid] = part[0][tid] + part[1][tid]
                                 + part[2][tid] + part[3][tid];
}

// One block (512 threads) per batch: parallel fp64 reduce of the 96 partials
// per shift-slot (6 threads/slot, 16 independent loads each), then argmax
// with first-index tie-break (strict > keeps lowest index).
__global__ __launch_bounds__(512) void k_argmax(const float* __restrict__ partials,
                                                int* __restrict__ best,
                                                float* __restrict__ outTail) {
    int b = blockIdx.x;
    int t = threadIdx.x;
    __shared__ double lds[486];
    __shared__ double vals[NS];
    if (t < 486) {
        int slot = t / 6;                 // 0..80
        int sub  = t % 6;
        int sxi = slot / 9, syi = slot % 9;
        int sxg = sxi / 3;
        int within = (sxi - sxg * 3) * 9 + syi;
        double acc = 0.0;
#pragma unroll
        for (int k = 0; k < 16; ++k) {    // 16 values each
            int q  = sub * 16 + k;        // q in [0, 96)
            int c  = q >> 5;              // q / 32
            int st = q & 31;              // q % 32
            int pb = ((b * CC + c) * NSTRIP + st) * NSXG + sxg;
            acc += (double)partials[pb * 27 + within];
        }
        lds[t] = acc;
    }
    __syncthreads();
    if (t < NS) {
        double s = 0.0;
#pragma unroll
        for (int k = 0; k < 6; ++k) s += lds[t * 6 + k];
        vals[t] = s;
    }
    __syncthreads();
    if (t == 0) {
        double bv = vals[0];
        int bi = 0;
        for (int s = 1; s < NS; ++s)
            if (vals[s] > bv) { bv = vals[s]; bi = s; }
        int sx = bi / 9 - 4;
        int sy = bi % 9 - 4;
        best[b * 2]     = sx;
        best[b * 2 + 1] = sy;
        outTail[b * 2]     = (float)sx;
        outTail[b * 2 + 1] = (float)sy;
    }
}

// out[b,c,i,j] = in-bounds(i-sx, j-sy) ? x[b,c,i-sx,j-sy] : 0
// One block = 2 rows of one (b,c) image; fast path = offset float4 load.
__global__ __launch_bounds__(256) void k_apply(const float* __restrict__ x,
                                               const int* __restrict__ best,
                                               float* __restrict__ out) {
    int blk = blockIdx.x;
    int bc  = blk >> 8;                 // 256 blocks per image (512 rows / 2)
    int tid = threadIdx.x;
    int row = ((blk & 255) << 1) + (tid >> 7);
    int j0  = (tid & 127) << 2;
    int b   = bc / CC;                  // block-uniform -> scalar loads of best
    int sx  = best[b * 2];
    int sy  = best[b * 2 + 1];
    int is  = row - sx;
    float4 v = make_float4(0.f, 0.f, 0.f, 0.f);
    if ((unsigned)is < HH) {
        const float* src = x + (size_t)bc * IMG + is * WW;
        int js0 = j0 - sy;
        if (js0 >= 0 && js0 + 3 < WW) {
            v = *(const float4*)(src + js0);   // 4B-aligned dwordx4, exact (R2-R9)
        } else {
            float* vv = (float*)&v;
#pragma unroll
            for (int k = 0; k < 4; ++k) {
                int js = js0 + k;
                if ((unsigned)js < WW) vv[k] = src[js];
            }
        }
    }
    *(float4*)(out + (size_t)bc * IMG + row * WW + j0) = v;
}

extern "C" void kernel_launch(void* const* d_in, const int* in_sizes, int n_in,
                              void* d_out, int out_size, void* d_ws, size_t ws_size,
                              hipStream_t stream) {
    const float* xref = (const float*)d_in[0];
    const float* x    = (const float*)d_in[1];
    float* out = (float*)d_out;

    float* partials = (float*)d_ws;
    int*   best     = (int*)((char*)d_ws + BEST_OFF);

    k_sims<<<NBLK, 256, 0, stream>>>(xref, x, partials);

    k_argmax<<<BB, 512, 0, stream>>>(partials, best, out + (size_t)BB * CHW);

    int applyBlocks = (BB * CC * HH) / 2;   // 3072
    k_apply<<<applyBlocks, 256, 0, stream>>>(x, best, out);
}

// Round 11
// 108.962 us; speedup vs baseline: 1.7472x; 1.0482x over previous
//
#include <hip/hip_runtime.h>

#define BB 4
#define CC 3
#define HH 512
#define WW 512
#define NS 81              // 9 x 9 shifts
#define IMG (HH * WW)
#define CHW (CC * IMG)
#define STRIP 32           // rows per k_sims block (8 rows per wave)
#define NSTRIP (HH / STRIP)              // 16
#define NBLK (BB * CC * NSTRIP * 9)      // 1728 blocks (one sx each)

// ws layout: double sims[BB][81] at byte 0 (2592 B, zeroed by a memset node).

// constant-index component select (folds after full unroll)
#define C4(v, i) ((i) == 0 ? (v).x : (i) == 1 ? (v).y : (i) == 2 ? (v).z : (v).w)

// sim(b,sx,sy) = sum over c,i,j (both (i,j) and (i+sx,j+sy) in bounds) of
//               x[b,c,i,j] * x_ref[b,c,i+sx,j+sy]
// R8 body verbatim (best-measured total; 5 structural rewrites of this loop
// all plateau at ~32-40us -> stop editing it). Only the epilogue changed:
// fp64 atomicAdd of the block's 9 fp32 partials into sims[b][81], which
// removes the separate k_argmax kernel (R11's one lever: graph shape).
__global__ __launch_bounds__(256, 4) void k_sims(const float* __restrict__ xref,
                                                 const float* __restrict__ x,
                                                 double* __restrict__ sims) {
    int bid  = blockIdx.x;
    int sxi  = bid % 9;                  // sx = sxi - 4
    int tmp  = bid / 9;
    int strip = tmp % NSTRIP;
    int bc   = tmp / NSTRIP;
    int b    = bc / CC;
    const float* xp = x    + (size_t)bc * IMG;
    const float* rp = xref + (size_t)bc * IMG;
    int tid  = threadIdx.x;
    int lane = tid & 63;
    int wave = tid >> 6;
    int j0   = lane << 3;                // 8 floats per lane
    int sx   = sxi - 4;
    int ip0  = strip * STRIP + wave * 8;

    float acc[9];
#pragma unroll
    for (int s = 0; s < 9; ++s) acc[s] = 0.f;

#pragma unroll
    for (int rr = 0; rr < 8; ++rr) {
        int ip = ip0 + rr;               // x row (always in bounds)
        int ii = ip + sx;                // ref row (wave-uniform test)
        if ((unsigned)ii >= HH) continue;

        const float* xrow = xp + ip * WW + j0;
        const float* rrow = rp + ii * WW + j0;
        float4 xa = *(const float4*)(xrow);        // x   cols j0   .. j0+3
        float4 xb = *(const float4*)(xrow + 4);    // x   cols j0+4 .. j0+7
        float4 ra = *(const float4*)(rrow);        // ref cols j0   .. j0+3
        float4 rb = *(const float4*)(rrow + 4);    // ref cols j0+4 .. j0+7

        // halo: prev4 = ref cols j0-4..j0-1 (lane-1's rb), next4 = j0+8..j0+11
        float p0 = __shfl_up(rb.x, 1, 64);
        float p1 = __shfl_up(rb.y, 1, 64);
        float p2 = __shfl_up(rb.z, 1, 64);
        float p3 = __shfl_up(rb.w, 1, 64);
        if (lane == 0) { p0 = p1 = p2 = p3 = 0.f; }   // cols < 0 -> mask
        float n0 = __shfl_down(ra.x, 1, 64);
        float n1 = __shfl_down(ra.y, 1, 64);
        float n2 = __shfl_down(ra.z, 1, 64);
        float n3 = __shfl_down(ra.w, 1, 64);
        if (lane == 63) { n0 = n1 = n2 = n3 = 0.f; }  // cols >= 512 -> mask

#define P4(i) ((i) == 0 ? p0 : (i) == 1 ? p1 : (i) == 2 ? p2 : p3)
#define N4(i) ((i) == 0 ? n0 : (i) == 1 ? n1 : (i) == 2 ? n2 : n3)
#pragma unroll
        for (int syi = 0; syi < 9; ++syi) {
#pragma unroll
            for (int k = 0; k < 8; ++k) {
                int i = k + syi;         // window index 0..15 (constant)
                float wv = (i < 4)  ? P4(i)
                         : (i < 8)  ? C4(ra, i - 4)
                         : (i < 12) ? C4(rb, i - 8)
                         :            N4(i - 12);
                float xv = (k < 4) ? C4(xa, k) : C4(xb, k - 4);
                acc[syi] += xv * wv;
            }
        }
#undef P4
#undef N4
    }

    // wave reduce (fp32), block combine in LDS, 9 fp64 atomics per block.
    // Numerics: fp32 block partials summed in fp64 (R2-proven); atomic order
    // nondeterminism ~1e-10 vs inter-sim gaps O(100) -> argmax stable.
    __shared__ float part[4][9];
#pragma unroll
    for (int s = 0; s < 9; ++s) {
        float v = acc[s];
        for (int off = 32; off; off >>= 1) v += __shfl_down(v, off, 64);
        if (lane == 0) part[wave][s] = v;
    }
    __syncthreads();
    if (tid < 9) {
        double tot = (double)part[0][tid] + (double)part[1][tid]
                   + (double)part[2][tid] + (double)part[3][tid];
        atomicAdd(&sims[b * NS + sxi * 9 + tid], tot);
    }
}

// Fused argmax + apply. Each block re-derives its batch's argmax from the
// 81 fp64 sims (L2-resident, 648 B) with first-index tie-break, then shifts
// its 2 rows. One designated block per batch also writes the shift tail.
__global__ __launch_bounds__(256) void k_apply(const float* __restrict__ x,
                                               const double* __restrict__ sims,
                                               float* __restrict__ out,
                                               float* __restrict__ outTail) {
    int blk = blockIdx.x;
    int bc  = blk >> 8;                 // 256 blocks per image (512 rows / 2)
    int tid = threadIdx.x;
    int b   = bc / CC;

    __shared__ double vals[NS];
    __shared__ int bestIdx;
    if (tid < NS) vals[tid] = sims[b * NS + tid];
    __syncthreads();
    if (tid < 64) {
        double v = vals[tid];
        int    i = tid;
        if (tid < NS - 64) {
            double v2 = vals[tid + 64];          // higher index: strict > only
            if (v2 > v) { v = v2; i = tid + 64; }
        }
        for (int off = 32; off; off >>= 1) {
            double ov = __shfl_down(v, off, 64);
            int    oi = __shfl_down(i, off, 64);
            if (ov > v || (ov == v && oi < i)) { v = ov; i = oi; }
        }
        if (tid == 0) bestIdx = i;
    }
    __syncthreads();
    int bi = bestIdx;
    int sx = bi / 9 - 4;
    int sy = bi % 9 - 4;
    if (blk == ((b * CC) << 8) && tid == 0) {    // one block per batch
        outTail[b * 2]     = (float)sx;
        outTail[b * 2 + 1] = (float)sy;
    }

    int row = ((blk & 255) << 1) + (tid >> 7);
    int j0  = (tid & 127) << 2;
    int is  = row - sx;
    float4 v = make_float4(0.f, 0.f, 0.f, 0.f);
    if ((unsigned)is < HH) {
        const float* src = x + (size_t)bc * IMG + is * WW;
        int js0 = j0 - sy;
        if (js0 >= 0 && js0 + 3 < WW) {
            v = *(const float4*)(src + js0);   // 4B-aligned dwordx4, exact (R2-R10)
        } else {
            float* vv = (float*)&v;
#pragma unroll
            for (int k = 0; k < 4; ++k) {
                int js = js0 + k;
                if ((unsigned)js < WW) vv[k] = src[js];
            }
        }
    }
    *(float4*)(out + (size_t)bc * IMG + row * WW + j0) = v;
}

extern "C" void kernel_launch(void* const* d_in, const int* in_sizes, int n_in,
                              void* d_out, int out_size, void* d_ws, size_t ws_size,
                              hipStream_t stream) {
    const float* xref = (const float*)d_in[0];
    const float* x    = (const float*)d_in[1];
    float* out = (float*)d_out;

    double* sims = (double*)d_ws;

    hipMemsetAsync(sims, 0, BB * NS * sizeof(double), stream);

    k_sims<<<NBLK, 256, 0, stream>>>(xref, x, sims);

    int applyBlocks = (BB * CC * HH) / 2;   // 3072
    k_apply<<<applyBlocks, 256, 0, stream>>>(x, sims, out, out + (size_t)BB * CHW);
}